// Round 9
// baseline (219.042 us; speedup 1.0000x reference)
//
#include <hip/hip_runtime.h>
#include <math.h>

#define DEVI static __device__ __forceinline__

using f16x8 = __attribute__((ext_vector_type(8))) _Float16;
using h16x2 = __attribute__((ext_vector_type(2))) __fp16;   // cvt_pkrtz native type
using f32x4  = __attribute__((ext_vector_type(4))) float;
using f32x16 = __attribute__((ext_vector_type(16))) float;

constexpr int Bb = 2, Tt = 2048, Dd = 2048, NQ = 16, NK = 4, HD = 128;
constexpr int Mrows = Bb * Tt;               // 4096
constexpr int QKVC  = NQ*HD + 2*NK*HD;       // 3072
constexpr int KOFF  = NQ*HD;                 // 2048
constexpr int VOFF  = NQ*HD + NK*HD;         // 2560

DEVI ushort f2h(float f) {                   // fp32 -> fp16 (RNE via v_cvt)
  _Float16 h = (_Float16)f;
  union { _Float16 h; ushort u; } v; v.h = h;
  return v.u;
}
DEVI float h2f(ushort u) {
  union { ushort u; _Float16 h; } v; v.u = u;
  return (float)v.h;
}

typedef const __attribute__((address_space(1))) unsigned* gp1;
typedef __attribute__((address_space(3))) unsigned* lp3;
DEVI void gload16(void* lds, const void* g) {
  __builtin_amdgcn_global_load_lds((gp1)g, (lp3)lds, 16, 0, 0);
}

// ---------------- fp32 -> fp16 convert (vectorized) ----------------
__global__ void k_cvt(const float* __restrict__ x, ushort* __restrict__ o, int n4) {
  int i = blockIdx.x * blockDim.x + threadIdx.x;
  if (i >= n4) return;
  float4 v = ((const float4*)x)[i];
  ushort4 u;
  u.x = f2h(v.x); u.y = f2h(v.y); u.z = f2h(v.z); u.w = f2h(v.w);
  ((ushort4*)o)[i] = u;
}

// ------- transpose + convert: in fp32 [R][C] -> out fp16 [C][R] -------
__global__ void k_tconv(const float* __restrict__ in, ushort* __restrict__ out, int R, int C) {
  __shared__ float t[32][33];
  const int c0 = blockIdx.x * 32, r0 = blockIdx.y * 32;
  const int tx = threadIdx.x, ty = threadIdx.y;
#pragma unroll
  for (int i = 0; i < 32; i += 8)
    t[ty + i][tx] = in[(size_t)(r0 + ty + i) * C + (c0 + tx)];
  __syncthreads();
#pragma unroll
  for (int i = 0; i < 32; i += 8)
    out[(size_t)(c0 + ty + i) * R + (r0 + tx)] = f2h(t[tx][ty + i]);
}

// ---------------- m97-style 128x128 fp16 GEMM, C = A * Bt^T ----------------
DEVI void stv(float* p, float v)  { *p = v; }
DEVI void stv(ushort* p, float v) { *p = f2h(v); }

template <typename OT>
__launch_bounds__(256)
__global__ void k_gemm_bt(const ushort* __restrict__ A, const ushort* __restrict__ Bt,
                          OT* __restrict__ C, int M, int N, int Kd) {
  __shared__ char As[8192];   // 128 rows x 64B (32 fp16), k-slot XOR swizzled
  __shared__ char Bs[8192];
  const int tid = threadIdx.x;
  const int l = tid & 63, w = tid >> 6;
  const int wr = w >> 1, wc = w & 1;
  const int lr = l & 15, lk = l >> 4;
  const size_t row0 = (size_t)blockIdx.y * 128, col0 = (size_t)blockIdx.x * 128;

  f32x4 acc[4][4];
#pragma unroll
  for (int i = 0; i < 4; ++i)
#pragma unroll
    for (int j = 0; j < 4; ++j) acc[i][j] = (f32x4){0.f, 0.f, 0.f, 0.f};

  const int c0i = tid, c1i = tid + 256;
  const int ra0 = c0i >> 2, sa0 = (c0i & 3) ^ ((ra0 >> 1) & 3);
  const int ra1 = c1i >> 2, sa1 = (c1i & 3) ^ ((ra1 >> 1) & 3);

  for (int kt = 0; kt < Kd; kt += 32) {
    if (kt) __syncthreads();
    gload16(As + c0i * 16, A + (row0 + ra0) * Kd + kt + sa0 * 8);
    gload16(As + c1i * 16, A + (row0 + ra1) * Kd + kt + sa1 * 8);
    gload16(Bs + c0i * 16, Bt + (col0 + ra0) * Kd + kt + sa0 * 8);
    gload16(Bs + c1i * 16, Bt + (col0 + ra1) * Kd + kt + sa1 * 8);
    __syncthreads();
    f16x8 af[4], bfr[4];
#pragma unroll
    for (int i = 0; i < 4; ++i) {
      int ra = wr * 64 + i * 16 + lr;
      af[i] = *(const f16x8*)(As + ra * 64 + ((lk ^ ((ra >> 1) & 3)) << 4));
      int rb = wc * 64 + i * 16 + lr;
      bfr[i] = *(const f16x8*)(Bs + rb * 64 + ((lk ^ ((rb >> 1) & 3)) << 4));
    }
#pragma unroll
    for (int i = 0; i < 4; ++i)
#pragma unroll
      for (int j = 0; j < 4; ++j)
        acc[i][j] = __builtin_amdgcn_mfma_f32_16x16x32_f16(af[i], bfr[j], acc[i][j], 0, 0, 0);
  }
#pragma unroll
  for (int i = 0; i < 4; ++i) {
    size_t r = row0 + wr * 64 + i * 16 + lk * 4;
#pragma unroll
    for (int j = 0; j < 4; ++j) {
      size_t cc = col0 + wc * 64 + j * 16 + lr;
#pragma unroll
      for (int rg = 0; rg < 4; ++rg) stv(&C[(r + rg) * N + cc], acc[i][j][rg]);
    }
  }
}

// ---------------- RoPE table (double-precision trig) ----------------
__global__ void k_rope_tab(const int* __restrict__ pos, float* __restrict__ tab) {
  int idx = blockIdx.x * blockDim.x + threadIdx.x;
  if (idx >= Mrows * 64) return;
  int m = idx >> 6, i = idx & 63;
  double a = (double)pos[m] * exp2(-0.20762050593045952 * (double)i);
  tab[idx * 2]     = (float)cos(a);
  tab[idx * 2 + 1] = (float)sin(a);
}

// ---------------- RoPE apply in-place on q,k columns of fp16 QKV ----------------
__global__ void k_rope(ushort* __restrict__ qkv, const float* __restrict__ tab) {
  int idx = blockIdx.x * blockDim.x + threadIdx.x;
  if (idx >= Mrows * 20 * 8) return;
  int chunk = idx & 7;          // 8 pairs each
  int h20 = (idx >> 3) % 20;    // 16 q heads + 4 k heads
  int m = idx / 160;
  int colbase = (h20 < 16) ? h20 * 128 : (KOFF + (h20 - 16) * 128);
  size_t base = (size_t)m * QKVC + colbase + chunk * 8;
  union { uint4 v; ushort s[8]; } A1, A2, O1, O2;
  A1.v = *(const uint4*)(qkv + base);
  A2.v = *(const uint4*)(qkv + base + 64);
  const float* tp = tab + ((size_t)m * 64 + chunk * 8) * 2;
#pragma unroll
  for (int j = 0; j < 8; ++j) {
    float c = tp[2 * j], s = tp[2 * j + 1];
    float x1 = h2f(A1.s[j]), x2 = h2f(A2.s[j]);
    O1.s[j] = f2h(x1 * c - x2 * s);
    O2.s[j] = f2h(x2 * c + x1 * s);
  }
  *(uint4*)(qkv + base) = O1.v;
  *(uint4*)(qkv + base + 64) = O2.v;
}

// ------- V transpose: QKV v-cols -> VT[(b*4+g)*128 + h][s'] -------
// s permuted within each 16-block: stored order [0-3, 8-11, 4-7, 12-15], so a
// contiguous 8-elem read at offset hi*8 delivers the BLOCKED MFMA B-operand
// pattern k = hi*4 + (e&3) + 8*(e>>2).
__global__ void k_vt(const ushort* __restrict__ qkv, ushort* __restrict__ vt) {
  __shared__ ushort t[32][33];
  const int bg = blockIdx.z, bq = bg >> 2, g = bg & 3;
  const int s0 = blockIdx.x * 32, h0 = blockIdx.y * 32;
  const int tx = threadIdx.x, ty = threadIdx.y;
#pragma unroll
  for (int i = 0; i < 32; i += 8)
    t[ty + i][tx] = qkv[(size_t)(bq * Tt + s0 + ty + i) * QKVC + VOFF + g * HD + h0 + tx];
  __syncthreads();
  const int sx = (tx & 3) | ((tx & 8) >> 1) | ((tx & 4) << 1) | (tx & 16);
#pragma unroll
  for (int i = 0; i < 32; i += 8)
    vt[((size_t)bg * HD + h0 + ty + i) * Tt + (s0 + sx)] = t[tx][ty + i];
}

// ---------------- causal GQA flash attention v6b: 32x32 MFMA, in-register P ----------------
// 256 threads / 4 waves; QB=128 (wave w: 32 q-rows); KVBLK=64.
// Swapped QK^T (mfma(K,Q)) -> lane holds P[q=lane&31][32 s] in the hardware
// D layout, which IS the blocked A-operand layout k=(l>>5)*4+(e&3)+8*(e>>2)
// after pairwise cvt_pkrtz packing -> P feeds PV directly, zero data movement.
// V^T pre-permuted in s (k_vt) so contiguous b128 reads give the blocked
// B-operand. Softmax = in-lane tree + 1 shfl_xor(32). Defer-max THR=8.
__launch_bounds__(256, 2)
__global__ void k_flash(const ushort* __restrict__ qkv, const ushort* __restrict__ vt,
                        ushort* __restrict__ attn) {
  __shared__ char Ks[2][16384];   // K [s=64][h=128] fp16, granule ^= (s&15)
  __shared__ char Vs[2][16384];   // V^T [h=128][s'=64] fp16, granule ^= (h&7)
  const int b = blockIdx.x;
  const int vv = b >> 8, u = b & 255;
  const int hid = u >> 3, p = u & 7;
  const int qt = vv ? p : (15 - p);           // paired workload balance
  const int bq = hid >> 4, n = hid & 15, g = n >> 2;
  const int tid = threadIdx.x, w = tid >> 6, l = tid & 63;
  const int q5 = l & 31, hi = l >> 5;
  const int t0 = qt * 128;
  const int qrow = t0 + w * 32;
  const int qglob = qrow + q5;                // this lane's q row

  // Q B-frag (addressing self-consistent with K A-frag; K-perm cancels)
  f16x8 qf[8];
  {
    const size_t qb = ((size_t)(bq * Tt + qglob)) * QKVC + n * HD + hi * 8;
#pragma unroll
    for (int kc = 0; kc < 8; ++kc) qf[kc] = *(const f16x8*)(qkv + qb + kc * 16);
  }
  f32x16 O[4];
#pragma unroll
  for (int ht = 0; ht < 4; ++ht)
#pragma unroll
    for (int r = 0; r < 16; ++r) O[ht][r] = 0.f;
  float m = -INFINITY, lsum = 0.f;            // softmax state for q = qglob

  const size_t kgbase = (size_t)(bq * Tt) * QKVC + KOFF + g * HD;
  const size_t vgbase = (size_t)(bq * 4 + g) * HD * Tt;
  const int ntiles = 2 * qt + 2;

#define STAGE(buf, s0s)                                                               \
  {                                                                                   \
    _Pragma("unroll")                                                                 \
    for (int cc = 0; cc < 4; ++cc) {                                                  \
      int c = cc * 256 + tid;                                                         \
      int sK = c >> 4, gK = (c & 15) ^ (sK & 15);                                     \
      gload16(Ks[buf] + c * 16, qkv + kgbase + (size_t)((s0s) + sK) * QKVC + gK * 8); \
      int hV = c >> 3, gV = (c & 7) ^ (hV & 7);                                       \
      gload16(Vs[buf] + c * 16, vt + vgbase + (size_t)hV * Tt + (s0s) + gV * 8);      \
    }                                                                                 \
  }

  STAGE(0, 0);
  __syncthreads();

  for (int j = 0; j < ntiles; ++j) {
    const int cur = j & 1;
    if (j + 1 < ntiles) STAGE(cur ^ 1, (j + 1) * 64);
    const int s0 = j * 64;
    if (s0 <= qrow + 31) {
      // QK^T swapped: sc[st][r] = S[q=qglob][s = s0 + st*32 + (r&3)+8*(r>>2)+4*hi]
      f32x16 sc[2];
      __builtin_amdgcn_s_setprio(1);
#pragma unroll
      for (int st = 0; st < 2; ++st) {
        f32x16 a;
#pragma unroll
        for (int r = 0; r < 16; ++r) a[r] = 0.f;
        const int sl = st * 32 + q5;
        const int ssw = (sl & 15) << 4;
#pragma unroll
        for (int kc = 0; kc < 8; ++kc) {
          f16x8 kf = *(const f16x8*)(Ks[cur] + sl * 256 + (((kc * 32 + hi * 16)) ^ ssw));
          a = __builtin_amdgcn_mfma_f32_32x32x16_f16(kf, qf[kc], a, 0, 0, 0);
        }
        sc[st] = a;
      }
      __builtin_amdgcn_s_setprio(0);
      if (s0 + 63 > qrow) {         // diagonal region: mask s > q
#pragma unroll
        for (int st = 0; st < 2; ++st)
#pragma unroll
          for (int r = 0; r < 16; ++r) {
            int sg = s0 + st * 32 + (r & 3) + 8 * (r >> 2) + 4 * hi;
            if (sg > qglob) sc[st][r] = -INFINITY;
          }
      }
      // row max: in-lane tree over 32 + 1 cross shuffle
      float pm = -INFINITY;
#pragma unroll
      for (int st = 0; st < 2; ++st)
#pragma unroll
        for (int r = 0; r < 16; ++r) pm = fmaxf(pm, sc[st][r]);
      pm = fmaxf(pm, __shfl_xor(pm, 32));
      const bool doresc = !__all(pm - m <= 8.0f);   // defer-max (THR=8)
      float scl = 1.f;
      if (doresc) { float mn = fmaxf(m, pm); scl = __expf(m - mn); m = mn; }
      // exp + row sum
      float rs = 0.f;
#pragma unroll
      for (int st = 0; st < 2; ++st)
#pragma unroll
        for (int r = 0; r < 16; ++r) { sc[st][r] = __expf(sc[st][r] - m); rs += sc[st][r]; }
      rs += __shfl_xor(rs, 32);
      if (doresc) {
        float sr[16];
#pragma unroll
        for (int r = 0; r < 16; ++r) sr[r] = __shfl(scl, (r & 3) + 8 * (r >> 2) + 4 * hi);
#pragma unroll
        for (int ht = 0; ht < 4; ++ht)
#pragma unroll
          for (int r = 0; r < 16; ++r) O[ht][r] *= sr[r];
        lsum = lsum * scl + rs;
      } else {
        lsum += rs;
      }
      // pack P pairwise to fp16: pw[st][w'] = regs (2w', 2w'+1).  In the blocked
      // operand layout these ARE the PV A-frag words: MFMA cc uses pw[cc>>1][(cc&1)*4 .. +3].
      unsigned pw[2][8];
#pragma unroll
      for (int st = 0; st < 2; ++st)
#pragma unroll
        for (int i = 0; i < 8; ++i) {
          union { h16x2 h; unsigned u; } t;
          t.h = __builtin_amdgcn_cvt_pkrtz(sc[st][2 * i], sc[st][2 * i + 1]);
          pw[st][i] = t.u;
        }
      // PV: O[q][h] += P[q][s] * V[s][h];  A = P words (direct), B = V^T (s-permuted)
      __builtin_amdgcn_s_setprio(1);
#pragma unroll
      for (int ht = 0; ht < 4; ++ht) {
        const int hrow = ht * 32 + q5;
        const int hsw = (hrow & 7) << 4;
#pragma unroll
        for (int cc = 0; cc < 4; ++cc) {
          const int st = cc >> 1, ch = cc & 1;
          union { unsigned u[4]; f16x8 v; } pa;
          pa.u[0] = pw[st][ch * 4 + 0];
          pa.u[1] = pw[st][ch * 4 + 1];
          pa.u[2] = pw[st][ch * 4 + 2];
          pa.u[3] = pw[st][ch * 4 + 3];
          f16x8 vf = *(const f16x8*)(Vs[cur] + hrow * 128 + (((cc * 2 + hi) << 4) ^ hsw));
          O[ht] = __builtin_amdgcn_mfma_f32_32x32x16_f16(pa.v, vf, O[ht], 0, 0, 0);
        }
      }
      __builtin_amdgcn_s_setprio(0);
    }
    __syncthreads();
  }
#undef STAGE
  float iv[16];
#pragma unroll
  for (int r = 0; r < 16; ++r) iv[r] = 1.f / __shfl(lsum, (r & 3) + 8 * (r >> 2) + 4 * hi);
#pragma unroll
  for (int ht = 0; ht < 4; ++ht)
#pragma unroll
    for (int r = 0; r < 16; ++r) {
      size_t orow = (size_t)(bq * Tt + qrow + (r & 3) + 8 * (r >> 2) + 4 * hi);
      attn[orow * 2048 + n * HD + ht * 32 + q5] = f2h(O[ht][r] * iv[r]);
    }
}

// ---------------- launch ----------------
extern "C" void kernel_launch(void* const* d_in, const int* in_sizes, int n_in,
                              void* d_out, int out_size, void* d_ws, size_t ws_size,
                              hipStream_t stream) {
  const float* X  = (const float*)d_in[0];
  const int*   qp = (const int*)d_in[1];
  const float* Wq = (const float*)d_in[2];
  const float* Wk = (const float*)d_in[3];
  const float* Wv = (const float*)d_in[4];
  const float* Wo = (const float*)d_in[5];
  float* out = (float*)d_out;
  char* ws = (char*)d_ws;

  ushort* Xf    = (ushort*)(ws + 0);          // 4096x2048 fp16      (16.78 MB)
  ushort* WqkvT = (ushort*)(ws + 16777216);   // 3072x2048 fp16      (12.58 MB)
  ushort* WoT   = (ushort*)(ws + 29360128);   // 2048x2048 fp16      ( 8.39 MB)
  ushort* QKV   = (ushort*)(ws + 37748736);   // 4096x3072 fp16      (25.17 MB)
  ushort* VT    = (ushort*)(ws + 62914560);   // 8x128x2048 fp16     ( 4.19 MB)
  ushort* attn  = (ushort*)(ws + 67108864);   // 4096x2048 fp16      (16.78 MB)
  float*  tab   = (float*)(ws + 83886080);    // 4096x64x2 f32       ( 2.10 MB)

  dim3 tb(32, 8);
  // 1. X -> fp16
  k_cvt<<<(Mrows * Dd / 4 + 255) / 256, 256, 0, stream>>>(X, Xf, Mrows * Dd / 4);
  // 2. weights -> fp16, transposed to [n][k] (B^T layout); Wq/Wk/Wv fused rows
  k_tconv<<<dim3(64, 64), tb, 0, stream>>>(Wq, WqkvT, Dd, NQ * HD);
  k_tconv<<<dim3(16, 64), tb, 0, stream>>>(Wk, WqkvT + (size_t)KOFF * Dd, Dd, NK * HD);
  k_tconv<<<dim3(16, 64), tb, 0, stream>>>(Wv, WqkvT + (size_t)VOFF * Dd, Dd, NK * HD);
  k_tconv<<<dim3(64, 64), tb, 0, stream>>>(Wo, WoT, NQ * HD, Dd);
  // 3. fused QKV projection (fp16 in, fp16 out)
  k_gemm_bt<ushort><<<dim3(QKVC / 128, Mrows / 128), 256, 0, stream>>>(
      Xf, WqkvT, QKV, Mrows, QKVC, Dd);
  // 4+5. RoPE (fp32 math, in-place on fp16 q,k)
  k_rope_tab<<<(Mrows * 64 + 255) / 256, 256, 0, stream>>>(qp, tab);
  k_rope<<<(Mrows * 160 + 255) / 256, 256, 0, stream>>>(QKV, tab);
  // 6. V transpose (s-permuted) for PV B-operand
  k_vt<<<dim3(Tt / 32, HD / 32, Bb * NK), tb, 0, stream>>>(QKV, VT);
  // 7. flash attention
  k_flash<<<dim3(512), 256, 0, stream>>>(QKV, VT, attn);
  // 8. output projection
  k_gemm_bt<float><<<dim3(Dd / 128, Mrows / 128), 256, 0, stream>>>(
      attn, WoT, out, Mrows, Dd, Dd);
}